// Round 3
// baseline (262.009 us; speedup 1.0000x reference)
//
#include <hip/hip_runtime.h>
#include <hip/hip_bf16.h>

// Problem dims (compile-time)
#define SDIM 512   // SEQDIM
#define EDIM 512   // EMBED_DIM
#define LDIM 384   // VFEAT_LEN
#define DDIM 384   // VFEAT_DIM

typedef __attribute__((ext_vector_type(4))) float float4v;

// ---------------------------------------------------------------------------
// Kernel 1: t[e][l] = tanh( sum_k wv[e][k]*v[k][l] + gh[e] ),  gh = wg @ h
// 2-row register tiling (halves v L2 traffic: 295 -> 148 MB) + 16-deep load
// batches (16 outstanding L2 loads per wave to hide ~200cy latency).
// 256 blocks x 384 threads (thread = column), 1 block/CU, 6 waves/CU.
// ---------------------------------------------------------------------------
__global__ __launch_bounds__(384) void k_tanh_s(
    const float* __restrict__ h, const float* __restrict__ v,
    const float* __restrict__ wv, const float* __restrict__ wg,
    float* __restrict__ t)
{
    const int e0  = blockIdx.x * 2;
    const int tid = threadIdx.x;            // 0..383 = column l
    __shared__ float wvs0[DDIM], wvs1[DDIM];
    __shared__ float red[2][6];

    // gh for both rows, all 384 threads
    float g0 = 0.f, g1 = 0.f;
    for (int k = tid; k < SDIM; k += 384) {
        const float hk = h[k];
        g0 += wg[e0 * SDIM + k] * hk;
        g1 += wg[(e0 + 1) * SDIM + k] * hk;
    }
    for (int off = 32; off > 0; off >>= 1) {
        g0 += __shfl_down(g0, off, 64);
        g1 += __shfl_down(g1, off, 64);
    }
    if ((tid & 63) == 0) { red[0][tid >> 6] = g0; red[1][tid >> 6] = g1; }

    wvs0[tid] = wv[e0 * DDIM + tid];
    wvs1[tid] = wv[(e0 + 1) * DDIM + tid];
    __syncthreads();

    const float gh0 = ((red[0][0] + red[0][1]) + (red[0][2] + red[0][3]))
                      + (red[0][4] + red[0][5]);
    const float gh1 = ((red[1][0] + red[1][1]) + (red[1][2] + red[1][3]))
                      + (red[1][4] + red[1][5]);

    const float* vp = v + tid;
    float a[4] = {0.f, 0.f, 0.f, 0.f};
    float b[4] = {0.f, 0.f, 0.f, 0.f};
    for (int kb = 0; kb < DDIM; kb += 16) {   // 24 iters
        float vv[16];
        #pragma unroll
        for (int u = 0; u < 16; ++u)          // 16 loads in flight
            vv[u] = vp[(kb + u) * LDIM];
        #pragma unroll
        for (int u = 0; u < 16; ++u) {        // each load feeds 2 FMAs
            a[u & 3] += wvs0[kb + u] * vv[u];
            b[u & 3] += wvs1[kb + u] * vv[u];
        }
    }
    t[e0 * LDIM + tid]       = tanhf((a[0] + a[1]) + (a[2] + a[3]) + gh0);
    t[(e0 + 1) * LDIM + tid] = tanhf((b[0] + b[1]) + (b[2] + b[3]) + gh1);
}

// ---------------------------------------------------------------------------
// Kernel 2: z[r][c] = sum_e wh[r][e] * t[e][c]; alpha[r][:] = softmax(z[r][:])
// Same treatment: 2-row tiling (t traffic 302 -> 151 MB) + 16-deep batches.
// 192 blocks x 384 threads (thread = column); z in registers; softmax for
// both rows via shfl + tiny LDS reduce.
// ---------------------------------------------------------------------------
__global__ __launch_bounds__(384) void k_softmax(
    const float* __restrict__ wh, const float* __restrict__ t,
    float* __restrict__ alpha)
{
    const int r0  = blockIdx.x * 2;
    const int tid = threadIdx.x;            // 0..383 = column c
    __shared__ float whs0[EDIM], whs1[EDIM];
    __shared__ float redm[2][6], reds[2][6];

    for (int e = tid; e < EDIM; e += 384) {
        whs0[e] = wh[r0 * EDIM + e];
        whs1[e] = wh[(r0 + 1) * EDIM + e];
    }
    __syncthreads();

    const float* tp = t + tid;
    float a[4] = {0.f, 0.f, 0.f, 0.f};
    float b[4] = {0.f, 0.f, 0.f, 0.f};
    for (int eb = 0; eb < EDIM; eb += 16) {   // 32 iters
        float tv[16];
        #pragma unroll
        for (int u = 0; u < 16; ++u)
            tv[u] = tp[(eb + u) * LDIM];
        #pragma unroll
        for (int u = 0; u < 16; ++u) {
            a[u & 3] += whs0[eb + u] * tv[u];
            b[u & 3] += whs1[eb + u] * tv[u];
        }
    }
    const float z0 = (a[0] + a[1]) + (a[2] + a[3]);
    const float z1 = (b[0] + b[1]) + (b[2] + b[3]);

    // block max (both rows in one shfl chain)
    float m0 = z0, m1 = z1;
    for (int off = 32; off > 0; off >>= 1) {
        m0 = fmaxf(m0, __shfl_down(m0, off, 64));
        m1 = fmaxf(m1, __shfl_down(m1, off, 64));
    }
    if ((tid & 63) == 0) { redm[0][tid >> 6] = m0; redm[1][tid >> 6] = m1; }
    __syncthreads();
    m0 = fmaxf(fmaxf(fmaxf(redm[0][0], redm[0][1]), fmaxf(redm[0][2], redm[0][3])),
               fmaxf(redm[0][4], redm[0][5]));
    m1 = fmaxf(fmaxf(fmaxf(redm[1][0], redm[1][1]), fmaxf(redm[1][2], redm[1][3])),
               fmaxf(redm[1][4], redm[1][5]));

    const float e0 = expf(z0 - m0);
    const float e1 = expf(z1 - m1);

    float s0 = e0, s1 = e1;
    for (int off = 32; off > 0; off >>= 1) {
        s0 += __shfl_down(s0, off, 64);
        s1 += __shfl_down(s1, off, 64);
    }
    if ((tid & 63) == 0) { reds[0][tid >> 6] = s0; reds[1][tid >> 6] = s1; }
    __syncthreads();
    const float rs0 = 1.f / (((reds[0][0] + reds[0][1]) + (reds[0][2] + reds[0][3]))
                             + (reds[0][4] + reds[0][5]));
    const float rs1 = 1.f / (((reds[1][0] + reds[1][1]) + (reds[1][2] + reds[1][3]))
                             + (reds[1][4] + reds[1][5]));

    alpha[r0 * LDIM + tid]       = e0 * rs0;
    alpha[(r0 + 1) * LDIM + tid] = e1 * rs1;
}

// ---------------------------------------------------------------------------
// Kernel 3: out[i][j][k] = v[j][k] * alpha[i][j]   (226.5 MB f32 writes)
// Pure-store steady state (the fill-kernel profile): loads and stores share
// vmcnt, so the old interleaved load->store chain stalled loads behind store
// acks. Now each block loads its 24-row v-tile into REGISTERS once (9 vec4
// per thread) and a 16x24 alpha tile into LDS once; the hot loop is
// LDS-read + mul + store only.
// Grid: 16 j-tiles x 24 i-tiles = 384 blocks x 256 threads.
// ---------------------------------------------------------------------------
__global__ __launch_bounds__(256) void k_out(
    const float* __restrict__ v, const float* __restrict__ alpha,
    float* __restrict__ out)
{
    constexpr int VPS = (LDIM * DDIM) / 4;   // 36864 vec4 per i-slice
    const int jt = blockIdx.x & 15;          // j-tile: rows j0..j0+23 of v
    const int it = blockIdx.x >> 4;          // i-tile: slices i0..i0+15
    const int j0 = jt * 24;
    const int i0 = it * 16;
    const int tid = (int)threadIdx.x;

    __shared__ float al[16][24];             // alpha[i0+ii][j0+jj]
    for (int x = tid; x < 16 * 24; x += 256) {
        const int ii = x / 24;
        const int jj = x - ii * 24;
        al[ii][jj] = alpha[(i0 + ii) * LDIM + j0 + jj];
    }

    // v-tile into registers: tile = 24 rows x 96 vec4 = 2304 vec4, 9/thread
    const float4v* v4 = (const float4v*)v;
    float4v vr[9];
    int jj[9];
    #pragma unroll
    for (int k = 0; k < 9; ++k) {
        const int x = k * 256 + tid;         // 0..2303 within tile
        vr[k] = v4[j0 * 96 + x];
        jj[k] = x / 96;                      // row within tile (0..23)
    }
    __syncthreads();

    float4v* o4 = (float4v*)out;
    size_t base = (size_t)i0 * VPS + j0 * 96;
    for (int ii = 0; ii < 16; ++ii) {        // per i: 36 KB contiguous stores
        #pragma unroll
        for (int k = 0; k < 9; ++k)
            o4[base + k * 256 + tid] = vr[k] * al[ii][jj[k]];
        base += VPS;
    }
}

// ---------------------------------------------------------------------------
extern "C" void kernel_launch(void* const* d_in, const int* in_sizes, int n_in,
                              void* d_out, int out_size, void* d_ws, size_t ws_size,
                              hipStream_t stream)
{
    const float* h  = (const float*)d_in[0];   // (512, 1)   f32
    const float* v  = (const float*)d_in[1];   // (384, 384) f32
    const float* wh = (const float*)d_in[2];   // (384, 512) f32
    const float* wv = (const float*)d_in[3];   // (512, 384) f32
    const float* wg = (const float*)d_in[4];   // (512, 512) f32
    float* out = (float*)d_out;                // (384, 384, 384) f32

    float* t     = (float*)d_ws;               // (512, 384) f32 scratch
    float* alpha = t + EDIM * LDIM;            // (384, 384) f32 scratch

    k_tanh_s <<<EDIM / 2, 384, 0, stream>>>(h, v, wv, wg, t);
    k_softmax<<<LDIM / 2, 384, 0, stream>>>(wh, t, alpha);
    k_out    <<<16 * 24, 256, 0, stream>>>(v, alpha, out);
}